// Round 18
// baseline (71.726 us; speedup 1.0000x reference)
//
#include <hip/hip_runtime.h>
#include <math.h>

#define NFFT   1024
#define FREQ   513
#define FRAMES 256
#define SIGLEN 66560          // 256*256 + 1024
#define NB     4
#define BFT    (NB * FREQ * FRAMES)   // 525312
#define NWAVE  4               // waves per block
#define NTHR   (64 * NWAVE)    // 256
#define NCHUNK 9               // ceil(513/64)
#define UNITS  (NCHUNK * FRAMES)      // 2304 blocks, 1 unit each (LPT order)

__device__ __forceinline__ float sigmoid_f32(float v)
{
    if (v >= 0.0f) {
        return 1.0f / (1.0f + expf(-v));
    } else {
        const float e = expf(v);
        return e / (1.0f + e);
    }
}

__device__ __forceinline__ float rfl_f32(float v)
{
    return __int_as_float(__builtin_amdgcn_readfirstlane(__float_as_int(v)));
}

__device__ __forceinline__ float rdlane_f32(float v, int k)
{
    return __uint_as_float(__builtin_amdgcn_readlane(__float_as_uint(v), k));
}

// ---------------------------------------------------------------------------
// Setup: sorted-f (desc theta, stable), per-chunk theta-max, per-frame
// {base, center} tables. ws layout (bytes): sf u16[513]@0, ctmax f32[9]@1028,
// tbase i32[256]@1064, tc f32[256]@2088 -> 3112 B total.
// ---------------------------------------------------------------------------
__global__ __launch_bounds__(1024)
void dstft_setup(const float* __restrict__ raw_win,
                 const float* __restrict__ raw_hop,
                 unsigned short* __restrict__ sf,
                 float* __restrict__ ctmax,
                 int* __restrict__ tbase,
                 float* __restrict__ tc)
{
    __shared__ float th[FREQ];
    const int tid = threadIdx.x;
    if (tid < FREQ)
        th[tid] = 10.0f + sigmoid_f32(raw_win[tid]) * 1014.0f;
    __syncthreads();
    if (tid < FREQ) {
        const float ti = th[tid];
        int r = 0;
        for (int j = 0; j < FREQ; ++j) {
            const float tj = th[j];
            r += (tj > ti) || (tj == ti && j < tid);   // descending, stable
        }
        sf[r] = (unsigned short)tid;
        if ((r & 63) == 0) ctmax[r >> 6] = ti;         // chunk max (desc)
    }
    if (tid < FRAMES) {
        // f32-canonical replication of the reference pos computation
        const float hop = 1.0f + sigmoid_f32(raw_hop[0]) * 255.0f;
        float pos = (float)tid * hop;
        pos = fminf(fmaxf(pos, 0.0f), 65536.0f);
        const float fl = floorf(pos);
        tbase[tid] = (int)fl;
        tc[tid]    = 511.5f + (pos - fl);
    }
}

// ---------------------------------------------------------------------------
// LDS-free feed: 2304 blocks (LPT order), 4 waves. Wave q processes 64-sample
// groups g = q, q+4, ... of the support [lo, lo+cnt). Per group: 4 coalesced
// dword loads (lane i = sample s_g+i, batches 0..3 in 4 VGPRs), then a
// 64-unrolled loop broadcasting sample k to all lanes via v_readlane (SGPR
// operand -> free in v_fmac). Over-run past hi is zeroed exactly by the
// med3+cos window (r > 0.5 -> w = 0); load addresses clamped to hi for
// safety. Phasor re-init per group (exact int reduction). No staging, no
// barriers until the final cross-wave combine. LDS = part[] only (9.2 KB).
// ---------------------------------------------------------------------------
__global__ __launch_bounds__(NTHR, 8)
void dstft_main(const float* __restrict__ x,
                const float* __restrict__ raw_win,
                const float* __restrict__ raw_hop,
                const unsigned short* __restrict__ sf,   // may be null
                const float* __restrict__ ctmax,
                const int* __restrict__ tbase,
                const float* __restrict__ tc,
                float* __restrict__ out, int out_size, int stft_mode)
{
    const int tid  = threadIdx.x;
    const int lane = tid & 63;
    const int q    = tid >> 6;               // wave id = batch in epilogue

    __shared__ float part[NWAVE][64][9];     // 9.2 KB

    const int u     = (int)blockIdx.x;
    const int chunk = u >> 8;                // 0..8 (desc-theta order)
    const int t     = u & 255;
    const int spos  = chunk * 64 + lane;
    const bool active = (spos < FREQ);

    int   f = 0;
    float theta, tmax, c;
    int   base;

    if (sf) {
        if (active) {
            f = (int)sf[spos];
            f = (f < 0) ? 0 : ((f > FREQ - 1) ? (FREQ - 1) : f);
        }
        theta = active ? (10.0f + sigmoid_f32(raw_win[f]) * 1014.0f) : 10.0f;
        tmax  = rfl_f32(ctmax[chunk]);
        base  = __builtin_amdgcn_readfirstlane(tbase[t]);
        c     = rfl_f32(tc[t]);
    } else {
        // fallback (no ws): natural f order, inline params
        if (active) f = spos;
        theta = active ? (10.0f + sigmoid_f32(raw_win[f]) * 1014.0f) : 10.0f;
        float tmaxv = theta;
#pragma unroll
        for (int s = 32; s; s >>= 1)
            tmaxv = fmaxf(tmaxv, __shfl_xor(tmaxv, s, 64));
        tmax = rfl_f32(tmaxv);
        const float hop = 1.0f + sigmoid_f32(raw_hop[0]) * 255.0f;
        float pos = (float)t * hop;
        pos = fminf(fmaxf(pos, 0.0f), 65536.0f);
        const float fl = floorf(pos);
        base = __builtin_amdgcn_readfirstlane((int)fl);
        c    = rfl_f32(511.5f + (pos - fl));
    }

    int lo = (int)floorf(c - 0.5f * tmax);
    int hi = (int)ceilf (c + 0.5f * tmax);
    lo = lo > 0 ? lo : 0;
    hi = hi < (NFFT - 1) ? hi : (NFFT - 1);
    int cnt = hi - lo + 1;
    cnt = cnt < 0 ? 0 : (cnt > NFFT ? NFFT : cnt);
    lo  = __builtin_amdgcn_readfirstlane(lo);
    cnt = __builtin_amdgcn_readfirstlane(cnt);
    const int his = lo + cnt - 1;            // scalar support end
    const int G   = (cnt + 63) >> 6;         // 64-sample groups

    const float invth = 1.0f / theta;
    const float sdr = (float)f * (1.0f / 1024.0f);
    const float cd  = __builtin_amdgcn_cosf(sdr);
    const float sd  = __builtin_amdgcn_sinf(sdr);

    float re0 = 0.f, re1 = 0.f, re2 = 0.f, re3 = 0.f;
    float im0 = 0.f, im1 = 0.f, im2 = 0.f, im3 = 0.f;

#pragma unroll 1
    for (int g = q; g < G; g += NWAVE) {
        const int sg = lo + (g << 6);
        // coalesced loads, address clamped to support end (over-run lanes
        // contribute w = 0, value irrelevant)
        int sidx = sg + lane;
        sidx = sidx < his ? sidx : his;
        const float* __restrict__ xa = x + base + sidx;
        const float xb0 = xa[0];
        const float xb1 = xa[SIGLEN];
        const float xb2 = xa[2 * SIGLEN];
        const float xb3 = xa[3 * SIGLEN];

        // window arg & phasor at group start (exact int reduction)
        const float rg = ((float)sg - c) * invth;
        int m0 = (f * sg) & (NFFT - 1);
        m0 = (m0 >= 512) ? (m0 - 1024) : m0;
        const float p0 = (float)m0 * (1.0f / 1024.0f);
        float pc = __builtin_amdgcn_cosf(p0);
        float ps = __builtin_amdgcn_sinf(p0);

#pragma unroll
        for (int k = 0; k < 64; ++k) {
            const float x0 = rdlane_f32(xb0, k);   // SGPR broadcast
            const float x1 = rdlane_f32(xb1, k);
            const float x2 = rdlane_f32(xb2, k);
            const float x3 = rdlane_f32(xb3, k);
            const float rk = fmaf((float)k, invth, rg);
            const float rc = __builtin_amdgcn_fmed3f(rk, -0.5f, 0.5f);
            const float w  = fmaf(0.5f, __builtin_amdgcn_cosf(rc), 0.5f);
            const float wc = w * pc;
            const float ws = w * ps;
            re0 = fmaf(x0, wc, re0);  im0 = fmaf(x0, ws, im0);
            re1 = fmaf(x1, wc, re1);  im1 = fmaf(x1, ws, im1);
            re2 = fmaf(x2, wc, re2);  im2 = fmaf(x2, ws, im2);
            re3 = fmaf(x3, wc, re3);  im3 = fmaf(x3, ws, im3);
            const float npc = fmaf(pc, cd, -(ps * sd));
            const float nps = fmaf(ps, cd,   pc * sd);
            pc = npc; ps = nps;
        }
    }

    // ---- cross-wave combine ----
    part[q][lane][0] = re0;  part[q][lane][1] = re1;
    part[q][lane][2] = re2;  part[q][lane][3] = re3;
    part[q][lane][4] = im0;  part[q][lane][5] = im1;
    part[q][lane][6] = im2;  part[q][lane][7] = im3;
    __syncthreads();

    // ---- epilogue: 4 waves in parallel, thread = (lane, batch=q) ----
    if (active) {
        float res = 0.f, sms = 0.f;
#pragma unroll
        for (int pw = 0; pw < NWAVE; ++pw) {
            res += part[pw][lane][q];
            sms += part[pw][lane][4 + q];
        }
        const float re = res;
        const float im = -sms;
        const int idx = q * (FREQ * FRAMES) + f * FRAMES + t;
        if (idx < out_size)
            out[idx] = sqrtf(fmaf(re, re, im * im)) + 1e-12f;   // spec
        if (stft_mode == 2) {
            if (BFT + 2 * idx + 1 < out_size) {
                out[BFT + 2 * idx]     = re;
                out[BFT + 2 * idx + 1] = im;
            }
        } else {
            if (BFT + idx < out_size)
                out[BFT + idx] = re;         // complex stored as f32 real
        }
    }
}

// ---------------------------------------------------------------------------
extern "C" void kernel_launch(void* const* d_in, const int* in_sizes, int n_in,
                              void* d_out, int out_size, void* d_ws, size_t ws_size,
                              hipStream_t stream)
{
    const float* x       = (const float*)d_in[0];
    const float* raw_win = (const float*)d_in[1];
    const float* raw_hop = (const float*)d_in[2];
    float* out = (float*)d_out;

    unsigned short* sf    = nullptr;
    float*          ctmax = nullptr;
    int*            tbase = nullptr;
    float*          tc    = nullptr;
    if (d_ws != nullptr && ws_size >= 3200) {
        sf    = (unsigned short*)d_ws;                   // 1028 B
        ctmax = (float*)((char*)d_ws + 1028);            // 36 B
        tbase = (int*)  ((char*)d_ws + 1064);            // 1024 B
        tc    = (float*)((char*)d_ws + 2088);            // 1024 B (end 3112)
        dstft_setup<<<1, 1024, 0, stream>>>(raw_win, raw_hop,
                                            sf, ctmax, tbase, tc);
    }
    const int stft_mode = (out_size >= 3 * BFT) ? 2 : 1;
    dstft_main<<<UNITS, NTHR, 0, stream>>>(
        x, raw_win, raw_hop, sf, ctmax, tbase, tc, out, out_size, stft_mode);
}